// Round 6
// baseline (901.152 us; speedup 1.0000x reference)
//
#include <hip/hip_runtime.h>

#define NDIM 64
#define NN   4096  // 64*64

using f32x4 = __attribute__((ext_vector_type(4))) float;
using s16x8 = __attribute__((ext_vector_type(8))) short;

// ---- bf16 helpers (RNE) ----------------------------------------------------
__device__ __forceinline__ ushort f2bf(float f) {
  uint u = __float_as_uint(f);
  u += 0x7fffu + ((u >> 16) & 1u);
  return (ushort)(u >> 16);
}
__device__ __forceinline__ float bf2f(ushort h) {
  return __uint_as_float(((uint)h) << 16);
}

// ---------------------------------------------------------------------------
// 256-thread 64x64 fp32 matmul on LDS: computes C[r][c] = sum_k A[k*64+r] *
// B[k*64+c] = (A^T B)[r][c] == (A*B)[r][c] when A is SYMMETRIC (true for all
// NS iterates here). Per-thread 4x4 tile; contiguous float4 reads.
// ---------------------------------------------------------------------------
__device__ __forceinline__ void mm64_256(const float* __restrict__ A,
                                         const float* __restrict__ B,
                                         float* __restrict__ C) {
  const int t  = threadIdx.x;
  const int r0 = (t >> 4) << 2;  // 16 row-groups of 4
  const int c0 = (t & 15) << 2;  // 16 col-groups of 4
  float acc[4][4];
#pragma unroll
  for (int i = 0; i < 4; ++i)
#pragma unroll
    for (int j = 0; j < 4; ++j) acc[i][j] = 0.f;
#pragma unroll 4
  for (int k = 0; k < NDIM; ++k) {
    const float4 a = *(const float4*)(A + k * NDIM + r0);
    const float4 b = *(const float4*)(B + k * NDIM + c0);
    const float av[4] = {a.x, a.y, a.z, a.w};
    const float bv[4] = {b.x, b.y, b.z, b.w};
#pragma unroll
    for (int i = 0; i < 4; ++i)
#pragma unroll
      for (int j = 0; j < 4; ++j) acc[i][j] += av[i] * bv[j];
  }
#pragma unroll
  for (int i = 0; i < 4; ++i)
    *(float4*)(C + (r0 + i) * NDIM + c0) =
        make_float4(acc[i][0], acc[i][1], acc[i][2], acc[i][3]);
}

// ---------------------------------------------------------------------------
// Newton–Schulz (cubic) matrix roots. block0: isqrtm(rm) -> ws[0..NN)
//                                     block1: sqrtm(bias) -> ws[NN..2NN)
// Y0 = A/c (c=||A||_F), Z0 = I; P=Z*Y; M=(15I-10P+3P^2)/8; Y'=Y*M; Z'=M*Z.
// Worst-case e0=0.944: .944->.82->.50->.097->4e-4->~1e-10. 6 iters safe.
// ---------------------------------------------------------------------------
__global__ __launch_bounds__(256) void ns_roots_kernel(
    const float* __restrict__ rm, const float* __restrict__ bias,
    float* __restrict__ ws) {
  __shared__ __align__(16) float bufs[4][NN];  // 64 KB
  const int t = threadIdx.x;
  const float* src = (blockIdx.x == 0) ? rm : bias;

  float* pY = bufs[0];
  float* pZ = bufs[1];
  float* pP = bufs[2];
  float* pS = bufs[3];

  float ssq = 0.f;
  for (int i = t; i < NN; i += 256) {
    const float v = src[i];
    pS[i] = v;
    ssq += v * v;
  }
  pP[t] = ssq;
  __syncthreads();
  for (int s = 128; s > 0; s >>= 1) {
    if (t < s) pP[t] += pP[t + s];
    __syncthreads();
  }
  const float c     = sqrtf(pP[0]);
  const float inv_c = 1.0f / c;
  __syncthreads();

  for (int i = t; i < NN; i += 256) {
    pY[i] = pS[i] * inv_c;
    pZ[i] = ((i & 63) == (i >> 6)) ? 1.f : 0.f;
  }
  __syncthreads();

  for (int it = 0; it < 6; ++it) {
    mm64_256(pZ, pY, pP);  __syncthreads();   // P = Z*Y  (Z sym)
    mm64_256(pP, pP, pS);  __syncthreads();   // S = P*P  (P sym)
    for (int i = t; i < NN; i += 256) {
      const float diag = ((i & 63) == (i >> 6)) ? 15.f : 0.f;
      pP[i] = (diag - 10.f * pP[i] + 3.f * pS[i]) * 0.125f;  // M in place
    }
    __syncthreads();
    mm64_256(pY, pP, pS);  __syncthreads();   // Ynew = Y*M (Y sym)
    mm64_256(pP, pZ, pY);  __syncthreads();   // Znew = M*Z (M sym)
    float* nY = pS;  float* nZ = pY;  float* nS = pZ;
    pY = nY; pZ = nZ; pS = nS;
  }

  if (blockIdx.x == 0) {
    const float s = 1.0f / sqrtf(c);
    for (int i = t; i < NN; i += 256) ws[i] = pZ[i] * s;        // isqrtm(rm)
  } else {
    const float s = sqrtf(c);
    for (int i = t; i < NN; i += 256) ws[NN + i] = pY[i] * s;   // sqrtm(bias)
  }
}

// ---------------------------------------------------------------------------
// L = sqb * isq  (row-major), split to bf16 hi/lo:
//   Lhi: ushort[4096] at ws+2NN, Llo: ushort[4096] at ws+2NN+2048 floats.
// L row-major serves BOTH MFMA operand roles in the apply kernel:
//   mm1 B-operand (B = L^T -> B^T-storage = L), mm2 A-operand (A = L).
// ---------------------------------------------------------------------------
__global__ __launch_bounds__(256) void lt_kernel(float* __restrict__ ws) {
  __shared__ __align__(16) float sA[NN];
  __shared__ __align__(16) float sB[NN];
  __shared__ __align__(16) float sC[NN];
  const int t = threadIdx.x;
  for (int i = t; i < NN; i += 256) {
    sA[i] = ws[NN + i];  // sqb (symmetric -> A of mm64_256)
    sB[i] = ws[i];       // isq
  }
  __syncthreads();
  mm64_256(sA, sB, sC);  // C = sqb * isq = L
  __syncthreads();
  ushort* Lhi = (ushort*)(ws + 2 * NN);
  ushort* Llo = (ushort*)(ws + 2 * NN + 2048);
  for (int i = t; i < NN; i += 256) {
    const float x = sC[i];
    const ushort h = f2bf(x);
    Lhi[i] = h;
    Llo[i] = f2bf(x - bf2f(h));
  }
}

// ---------------------------------------------------------------------------
// Apply: Y_b = L * X_b * L^T via split-bf16 MFMA (bf16xbf16 products are
// exact in fp32; 4 cross terms -> ~1e-6 rel accuracy, fp32 accumulate).
// Block = 256 thr = 4 waves, ONE matrix; wave w owns column strip 16w..16w+15.
//   mm1: U = X*L^T  -> C-frag (col=lane&15,row=4g+q, m89-verified) stored
//        TRANSPOSED to sU[col][row] (wave-private rows) as bf16 hi/lo.
//   mm2: Y = L*U    -> B-frag = U^T row-major = sU, contiguous reads.
// Fragment-load convention: A[row=lane&15, k=f(g,j)], B[col=lane&15,
// k=f(g,j)] with f(g,j)=8g+j. Correctness is INVARIANT to the hardware's
// actual A/B k-map: both operands use the same bijective f, and MFMA pairs
// same-(g,j) elements, so the dot product is a k-permutation of the true sum.
// Only the C/D map (m89/m91 HW-verified) is relied upon.
// All LDS tiles [64 rows][64 ushort] with XOR swizzle us ^= ((row&7)<<3):
// unswizzled, lanes 0-15 read 16 rows at 128B stride = 16-way conflict (G4);
// swizzled -> 2-way, free (m136). XOR touches only index bits 3-5 and every
// access is >=4-ushort aligned within an 8-group, so write/read agree.
// LDS 48 KB -> 3 blocks/CU (launch_bounds min-waves=3 caps VGPR at 168).
// ---------------------------------------------------------------------------
#define LDS_FRAG(buf, row, us) \
  (*(const s16x8*)&buf[(row) * 64 + ((us) ^ (((row) & 7) << 3))])

__global__ __launch_bounds__(256, 3) void bnspd_apply_mfma(
    const float* __restrict__ X, const float* __restrict__ ws,
    float* __restrict__ Yout) {
  __shared__ __align__(16) ushort sXhi[NN], sXlo[NN];
  __shared__ __align__(16) ushort sLhi[NN], sLlo[NN];
  __shared__ __align__(16) ushort sUhi[NN], sUlo[NN];
  const int t    = threadIdx.x;
  const int w    = t >> 6;
  const int lane = t & 63;
  const int lr   = lane & 15;
  const int g    = lane >> 4;
  const int b    = blockIdx.x;
  const float* __restrict__ Xg = X + (size_t)b * NN;

  // ---- stage L (already bf16 hi/lo in ws), apply swizzle ----
  const uint4* wsLhi = (const uint4*)(ws + 2 * NN);
  const uint4* wsLlo = (const uint4*)(ws + 2 * NN + 2048);
#pragma unroll
  for (int p = 0; p < 2; ++p) {
    const int c   = t + p * 256;  // 16B chunk id (512 total)
    const int e   = c * 8;        // ushort element index
    const int row = e >> 6;
    const int us  = e & 63;
    const int sw  = us ^ ((row & 7) << 3);
    *(uint4*)&sLhi[row * 64 + sw] = wsLhi[c];
    *(uint4*)&sLlo[row * 64 + sw] = wsLlo[c];
  }
  // ---- stage X, splitting fp32 -> bf16 hi/lo once ----
#pragma unroll
  for (int p = 0; p < 4; ++p) {
    const int fi  = t + p * 256;  // float4 id (1024 total)
    const int e   = fi * 4;
    const int row = e >> 6;
    const int col = e & 63;
    const float4 v = *(const float4*)(Xg + e);
    const ushort h0 = f2bf(v.x), h1 = f2bf(v.y), h2 = f2bf(v.z),
                 h3 = f2bf(v.w);
    const ushort l0 = f2bf(v.x - bf2f(h0)), l1 = f2bf(v.y - bf2f(h1)),
                 l2 = f2bf(v.z - bf2f(h2)), l3 = f2bf(v.w - bf2f(h3));
    uint2 hp, lp;
    hp.x = (uint)h0 | ((uint)h1 << 16);
    hp.y = (uint)h2 | ((uint)h3 << 16);
    lp.x = (uint)l0 | ((uint)l1 << 16);
    lp.y = (uint)l2 | ((uint)l3 << 16);
    const int sw = col ^ ((row & 7) << 3);
    *(uint2*)&sXhi[row * 64 + sw] = hp;
    *(uint2*)&sXlo[row * 64 + sw] = lp;
  }
  __syncthreads();

  const f32x4 zero = {0.f, 0.f, 0.f, 0.f};

  // ---- mm1: U = X * L^T ----
  f32x4 acc[4];
#pragma unroll
  for (int tm = 0; tm < 4; ++tm) acc[tm] = zero;
#pragma unroll
  for (int ks = 0; ks < 2; ++ks) {
    const int us = 32 * ks + 8 * g;
    const s16x8 bLh = LDS_FRAG(sLhi, 16 * w + lr, us);
    const s16x8 bLl = LDS_FRAG(sLlo, 16 * w + lr, us);
#pragma unroll
    for (int tm = 0; tm < 4; ++tm) {
      const s16x8 aXh = LDS_FRAG(sXhi, 16 * tm + lr, us);
      const s16x8 aXl = LDS_FRAG(sXlo, 16 * tm + lr, us);
      acc[tm] = __builtin_amdgcn_mfma_f32_16x16x32_bf16(aXh, bLh, acc[tm], 0, 0, 0);
      acc[tm] = __builtin_amdgcn_mfma_f32_16x16x32_bf16(aXh, bLl, acc[tm], 0, 0, 0);
      acc[tm] = __builtin_amdgcn_mfma_f32_16x16x32_bf16(aXl, bLh, acc[tm], 0, 0, 0);
      acc[tm] = __builtin_amdgcn_mfma_f32_16x16x32_bf16(aXl, bLl, acc[tm], 0, 0, 0);
    }
  }

  // ---- U C-frags -> sU (transposed), split bf16 hi/lo ----
  const int urow = 16 * w + lr;  // = U column = sU row (wave-private)
#pragma unroll
  for (int tm = 0; tm < 4; ++tm) {
    const int us = 16 * tm + 4 * g;
    const int sw = us ^ ((urow & 7) << 3);
    const ushort h0 = f2bf(acc[tm][0]), h1 = f2bf(acc[tm][1]),
                 h2 = f2bf(acc[tm][2]), h3 = f2bf(acc[tm][3]);
    const ushort l0 = f2bf(acc[tm][0] - bf2f(h0)),
                 l1 = f2bf(acc[tm][1] - bf2f(h1)),
                 l2 = f2bf(acc[tm][2] - bf2f(h2)),
                 l3 = f2bf(acc[tm][3] - bf2f(h3));
    uint2 hp, lp;
    hp.x = (uint)h0 | ((uint)h1 << 16);
    hp.y = (uint)h2 | ((uint)h3 << 16);
    lp.x = (uint)l0 | ((uint)l1 << 16);
    lp.y = (uint)l2 | ((uint)l3 << 16);
    *(uint2*)&sUhi[urow * 64 + sw] = hp;
    *(uint2*)&sUlo[urow * 64 + sw] = lp;
  }
  __syncthreads();

  // ---- mm2: Y = L * U ----
  f32x4 accY[4];
#pragma unroll
  for (int tm = 0; tm < 4; ++tm) accY[tm] = zero;
#pragma unroll
  for (int ks = 0; ks < 2; ++ks) {
    const int us = 32 * ks + 8 * g;
    const s16x8 bUh = LDS_FRAG(sUhi, 16 * w + lr, us);
    const s16x8 bUl = LDS_FRAG(sUlo, 16 * w + lr, us);
#pragma unroll
    for (int tm = 0; tm < 4; ++tm) {
      const s16x8 aLh = LDS_FRAG(sLhi, 16 * tm + lr, us);
      const s16x8 aLl = LDS_FRAG(sLlo, 16 * tm + lr, us);
      accY[tm] = __builtin_amdgcn_mfma_f32_16x16x32_bf16(aLh, bUh, accY[tm], 0, 0, 0);
      accY[tm] = __builtin_amdgcn_mfma_f32_16x16x32_bf16(aLh, bUl, accY[tm], 0, 0, 0);
      accY[tm] = __builtin_amdgcn_mfma_f32_16x16x32_bf16(aLl, bUh, accY[tm], 0, 0, 0);
      accY[tm] = __builtin_amdgcn_mfma_f32_16x16x32_bf16(aLl, bUl, accY[tm], 0, 0, 0);
    }
  }

  // ---- store Y: row = 16tm+4g+q, col = 16w+lr (16-lane 64B segments) ----
  float* __restrict__ Yg = Yout + (size_t)b * NN;
#pragma unroll
  for (int tm = 0; tm < 4; ++tm)
#pragma unroll
    for (int q = 0; q < 4; ++q)
      Yg[(16 * tm + 4 * g + q) * NDIM + 16 * w + lr] = accY[tm][q];
}

// ---------------------------------------------------------------------------
extern "C" void kernel_launch(void* const* d_in, const int* in_sizes, int n_in,
                              void* d_out, int out_size, void* d_ws,
                              size_t ws_size, hipStream_t stream) {
  const float* X    = (const float*)d_in[0];
  const float* rm   = (const float*)d_in[1];
  const float* bias = (const float*)d_in[2];
  float* out = (float*)d_out;
  float* ws  = (float*)d_ws;
  const int nmat = in_sizes[0] / NN;

  ns_roots_kernel<<<dim3(2), dim3(256), 0, stream>>>(rm, bias, ws);
  lt_kernel<<<dim3(1), dim3(256), 0, stream>>>(ws);
  bnspd_apply_mfma<<<dim3(nmat), dim3(256), 0, stream>>>(X, ws, out);
}

// Round 9
// 897.871 us; speedup vs baseline: 1.0037x; 1.0037x over previous
//
#include <hip/hip_runtime.h>

#define NDIM 64
#define NN   4096  // 64*64

using f32x4 = __attribute__((ext_vector_type(4))) float;
using s16x8 = __attribute__((ext_vector_type(8))) short;

// ---- bf16 helpers (RNE) ----------------------------------------------------
__device__ __forceinline__ ushort f2bf(float f) {
  uint u = __float_as_uint(f);
  u += 0x7fffu + ((u >> 16) & 1u);
  return (ushort)(u >> 16);
}
__device__ __forceinline__ float bf2f(ushort h) {
  return __uint_as_float(((uint)h) << 16);
}

// ---------------------------------------------------------------------------
// 256-thread 64x64 fp32 matmul on LDS: computes C[r][c] = sum_k A[k*64+r] *
// B[k*64+c] = (A^T B)[r][c] == (A*B)[r][c] when A is SYMMETRIC (true for all
// NS iterates here). Per-thread 4x4 tile; contiguous float4 reads.
// ---------------------------------------------------------------------------
__device__ __forceinline__ void mm64_256(const float* __restrict__ A,
                                         const float* __restrict__ B,
                                         float* __restrict__ C) {
  const int t  = threadIdx.x;
  const int r0 = (t >> 4) << 2;  // 16 row-groups of 4
  const int c0 = (t & 15) << 2;  // 16 col-groups of 4
  float acc[4][4];
#pragma unroll
  for (int i = 0; i < 4; ++i)
#pragma unroll
    for (int j = 0; j < 4; ++j) acc[i][j] = 0.f;
#pragma unroll 4
  for (int k = 0; k < NDIM; ++k) {
    const float4 a = *(const float4*)(A + k * NDIM + r0);
    const float4 b = *(const float4*)(B + k * NDIM + c0);
    const float av[4] = {a.x, a.y, a.z, a.w};
    const float bv[4] = {b.x, b.y, b.z, b.w};
#pragma unroll
    for (int i = 0; i < 4; ++i)
#pragma unroll
      for (int j = 0; j < 4; ++j) acc[i][j] += av[i] * bv[j];
  }
#pragma unroll
  for (int i = 0; i < 4; ++i)
    *(float4*)(C + (r0 + i) * NDIM + c0) =
        make_float4(acc[i][0], acc[i][1], acc[i][2], acc[i][3]);
}

// ---------------------------------------------------------------------------
// Newton–Schulz (cubic) matrix roots. block0: isqrtm(rm) -> ws[0..NN)
//                                     block1: sqrtm(bias) -> ws[NN..2NN)
// Y0 = A/c (c=||A||_F), Z0 = I; P=Z*Y; M=(15I-10P+3P^2)/8; Y'=Y*M; Z'=M*Z.
// Worst-case e0=0.944: .944->.82->.50->.097->4e-4->~1e-10. 6 iters safe.
// Verified round 6: absmax 0.0156 == split-bf16 noise, so NS converged.
// ---------------------------------------------------------------------------
__global__ __launch_bounds__(256) void ns_roots_kernel(
    const float* __restrict__ rm, const float* __restrict__ bias,
    float* __restrict__ ws) {
  __shared__ __align__(16) float bufs[4][NN];  // 64 KB
  const int t = threadIdx.x;
  const float* src = (blockIdx.x == 0) ? rm : bias;

  float* pY = bufs[0];
  float* pZ = bufs[1];
  float* pP = bufs[2];
  float* pS = bufs[3];

  float ssq = 0.f;
  for (int i = t; i < NN; i += 256) {
    const float v = src[i];
    pS[i] = v;
    ssq += v * v;
  }
  pP[t] = ssq;
  __syncthreads();
  for (int s = 128; s > 0; s >>= 1) {
    if (t < s) pP[t] += pP[t + s];
    __syncthreads();
  }
  const float c     = sqrtf(pP[0]);
  const float inv_c = 1.0f / c;
  __syncthreads();

  for (int i = t; i < NN; i += 256) {
    pY[i] = pS[i] * inv_c;
    pZ[i] = ((i & 63) == (i >> 6)) ? 1.f : 0.f;
  }
  __syncthreads();

  for (int it = 0; it < 6; ++it) {
    mm64_256(pZ, pY, pP);  __syncthreads();   // P = Z*Y  (Z sym)
    mm64_256(pP, pP, pS);  __syncthreads();   // S = P*P  (P sym)
    for (int i = t; i < NN; i += 256) {
      const float diag = ((i & 63) == (i >> 6)) ? 15.f : 0.f;
      pP[i] = (diag - 10.f * pP[i] + 3.f * pS[i]) * 0.125f;  // M in place
    }
    __syncthreads();
    mm64_256(pY, pP, pS);  __syncthreads();   // Ynew = Y*M (Y sym)
    mm64_256(pP, pZ, pY);  __syncthreads();   // Znew = M*Z (M sym)
    float* nY = pS;  float* nZ = pY;  float* nS = pZ;
    pY = nY; pZ = nZ; pS = nS;
  }

  if (blockIdx.x == 0) {
    const float s = 1.0f / sqrtf(c);
    for (int i = t; i < NN; i += 256) ws[i] = pZ[i] * s;        // isqrtm(rm)
  } else {
    const float s = sqrtf(c);
    for (int i = t; i < NN; i += 256) ws[NN + i] = pY[i] * s;   // sqrtm(bias)
  }
}

// ---------------------------------------------------------------------------
// L = sqb * isq  (row-major), split to bf16 hi/lo:
//   Lhi: ushort[4096] at ws+2NN, Llo: ushort[4096] at ws+2NN+2048 floats.
// L row-major serves BOTH MFMA operand roles in the apply kernel:
//   mm1 B-operand (B = L^T -> B^T-storage = L), mm2 A-operand (A = L).
// ---------------------------------------------------------------------------
__global__ __launch_bounds__(256) void lt_kernel(float* __restrict__ ws) {
  __shared__ __align__(16) float sA[NN];
  __shared__ __align__(16) float sB[NN];
  __shared__ __align__(16) float sC[NN];
  const int t = threadIdx.x;
  for (int i = t; i < NN; i += 256) {
    sA[i] = ws[NN + i];  // sqb (symmetric -> A of mm64_256)
    sB[i] = ws[i];       // isq
  }
  __syncthreads();
  mm64_256(sA, sB, sC);  // C = sqb * isq = L
  __syncthreads();
  ushort* Lhi = (ushort*)(ws + 2 * NN);
  ushort* Llo = (ushort*)(ws + 2 * NN + 2048);
  for (int i = t; i < NN; i += 256) {
    const float x = sC[i];
    const ushort h = f2bf(x);
    Lhi[i] = h;
    Llo[i] = f2bf(x - bf2f(h));
  }
}

// ---------------------------------------------------------------------------
// Apply v2: Y_b = L * X_b * L^T via split-bf16 MFMA.
// Round-6 measured: passed, absmax 0.0156 (= 2-term split noise). This rev
// targets latency hiding: X and U now SHARE one LDS buffer pair (sQ) -- X is
// dead after mm1, and the U-write -> mm2 B-read dependency is WITHIN-WAVE
// (wave w writes rows 16w+lr and reads only those rows), so lgkmcnt orders
// it without a barrier. The mm1->U-write hazard (other waves still reading
// X) needs the one barrier after mm1. LDS: 48 KB -> 32 KB, 3 -> 4 blocks/CU
// (16 waves/CU), launch_bounds(256,4) caps VGPR at 128.
// Phases: stage(L,X) -> bar -> mm1 -> bar -> Uwrite -> mm2 -> store.
// Fragment-load convention: A[row=lane&15, k=f(g,j)], B[col=lane&15,
// k=f(g,j)], f(g,j)=8g+j -- correctness invariant to the HW A/B k-map (both
// operands use the same bijective f). Only the C/D map (m89-verified,
// col=lane&15, row=4g+q) is relied on.
// LDS tiles [64 rows][64 ushort], XOR swizzle us ^= ((row&7)<<3): kills the
// 16-way conflict of 128B-stride row reads (G4); all accesses >=4-ushort
// aligned so write/read permutations agree.
// ---------------------------------------------------------------------------
#define LDS_FRAG(buf, row, us) \
  (*(const s16x8*)&buf[(row) * 64 + ((us) ^ (((row) & 7) << 3))])

__global__ __launch_bounds__(256, 4) void bnspd_apply_mfma(
    const float* __restrict__ X, const float* __restrict__ ws,
    float* __restrict__ Yout) {
  __shared__ __align__(16) ushort sQhi[NN], sQlo[NN];  // X, then U^T
  __shared__ __align__(16) ushort sLhi[NN], sLlo[NN];
  const int t    = threadIdx.x;
  const int w    = t >> 6;
  const int lane = t & 63;
  const int lr   = lane & 15;
  const int g    = lane >> 4;
  const int b    = blockIdx.x;
  const float* __restrict__ Xg = X + (size_t)b * NN;

  // ---- stage L (already bf16 hi/lo in ws), apply swizzle ----
  const uint4* wsLhi = (const uint4*)(ws + 2 * NN);
  const uint4* wsLlo = (const uint4*)(ws + 2 * NN + 2048);
#pragma unroll
  for (int p = 0; p < 2; ++p) {
    const int c   = t + p * 256;  // 16B chunk id (512 total)
    const int e   = c * 8;        // ushort element index
    const int row = e >> 6;
    const int us  = e & 63;
    const int sw  = us ^ ((row & 7) << 3);
    *(uint4*)&sLhi[row * 64 + sw] = wsLhi[c];
    *(uint4*)&sLlo[row * 64 + sw] = wsLlo[c];
  }
  // ---- stage X into sQ, splitting fp32 -> bf16 hi/lo once ----
#pragma unroll
  for (int p = 0; p < 4; ++p) {
    const int fi  = t + p * 256;  // float4 id (1024 total)
    const int e   = fi * 4;
    const int row = e >> 6;
    const int col = e & 63;
    const float4 v = *(const float4*)(Xg + e);
    const ushort h0 = f2bf(v.x), h1 = f2bf(v.y), h2 = f2bf(v.z),
                 h3 = f2bf(v.w);
    const ushort l0 = f2bf(v.x - bf2f(h0)), l1 = f2bf(v.y - bf2f(h1)),
                 l2 = f2bf(v.z - bf2f(h2)), l3 = f2bf(v.w - bf2f(h3));
    uint2 hp, lp;
    hp.x = (uint)h0 | ((uint)h1 << 16);
    hp.y = (uint)h2 | ((uint)h3 << 16);
    lp.x = (uint)l0 | ((uint)l1 << 16);
    lp.y = (uint)l2 | ((uint)l3 << 16);
    const int sw = col ^ ((row & 7) << 3);
    *(uint2*)&sQhi[row * 64 + sw] = hp;
    *(uint2*)&sQlo[row * 64 + sw] = lp;
  }
  __syncthreads();

  const f32x4 zero = {0.f, 0.f, 0.f, 0.f};

  // ---- mm1: U = X * L^T  (A = X rows from sQ, B^T-storage = L rows) ----
  f32x4 acc[4];
#pragma unroll
  for (int tm = 0; tm < 4; ++tm) acc[tm] = zero;
#pragma unroll
  for (int ks = 0; ks < 2; ++ks) {
    const int us = 32 * ks + 8 * g;
    const s16x8 bLh = LDS_FRAG(sLhi, 16 * w + lr, us);
    const s16x8 bLl = LDS_FRAG(sLlo, 16 * w + lr, us);
#pragma unroll
    for (int tm = 0; tm < 4; ++tm) {
      const s16x8 aXh = LDS_FRAG(sQhi, 16 * tm + lr, us);
      const s16x8 aXl = LDS_FRAG(sQlo, 16 * tm + lr, us);
      acc[tm] = __builtin_amdgcn_mfma_f32_16x16x32_bf16(aXh, bLh, acc[tm], 0, 0, 0);
      acc[tm] = __builtin_amdgcn_mfma_f32_16x16x32_bf16(aXh, bLl, acc[tm], 0, 0, 0);
      acc[tm] = __builtin_amdgcn_mfma_f32_16x16x32_bf16(aXl, bLh, acc[tm], 0, 0, 0);
      acc[tm] = __builtin_amdgcn_mfma_f32_16x16x32_bf16(aXl, bLl, acc[tm], 0, 0, 0);
    }
  }
  __syncthreads();  // all waves done reading X before sQ is overwritten

  // ---- U C-frags -> sQ (transposed = U^T row-major), split bf16 hi/lo ----
  // Wave-private rows 16w+lr; mm2 below reads ONLY these same rows, so the
  // dependency is within-wave and lgkmcnt (compiler-inserted) suffices.
  const int urow = 16 * w + lr;  // = U column = sQ row
#pragma unroll
  for (int tm = 0; tm < 4; ++tm) {
    const int us = 16 * tm + 4 * g;
    const int sw = us ^ ((urow & 7) << 3);
    const ushort h0 = f2bf(acc[tm][0]), h1 = f2bf(acc[tm][1]),
                 h2 = f2bf(acc[tm][2]), h3 = f2bf(acc[tm][3]);
    const ushort l0 = f2bf(acc[tm][0] - bf2f(h0)),
                 l1 = f2bf(acc[tm][1] - bf2f(h1)),
                 l2 = f2bf(acc[tm][2] - bf2f(h2)),
                 l3 = f2bf(acc[tm][3] - bf2f(h3));
    uint2 hp, lp;
    hp.x = (uint)h0 | ((uint)h1 << 16);
    hp.y = (uint)h2 | ((uint)h3 << 16);
    lp.x = (uint)l0 | ((uint)l1 << 16);
    lp.y = (uint)l2 | ((uint)l3 << 16);
    *(uint2*)&sQhi[urow * 64 + sw] = hp;
    *(uint2*)&sQlo[urow * 64 + sw] = lp;
  }

  // ---- mm2: Y = L * U  (A = L rows, B^T-storage = U^T rows from sQ) ----
  f32x4 accY[4];
#pragma unroll
  for (int tm = 0; tm < 4; ++tm) accY[tm] = zero;
#pragma unroll
  for (int ks = 0; ks < 2; ++ks) {
    const int us = 32 * ks + 8 * g;
    const s16x8 bUh = LDS_FRAG(sQhi, 16 * w + lr, us);
    const s16x8 bUl = LDS_FRAG(sQlo, 16 * w + lr, us);
#pragma unroll
    for (int tm = 0; tm < 4; ++tm) {
      const s16x8 aLh = LDS_FRAG(sLhi, 16 * tm + lr, us);
      const s16x8 aLl = LDS_FRAG(sLlo, 16 * tm + lr, us);
      accY[tm] = __builtin_amdgcn_mfma_f32_16x16x32_bf16(aLh, bUh, accY[tm], 0, 0, 0);
      accY[tm] = __builtin_amdgcn_mfma_f32_16x16x32_bf16(aLh, bUl, accY[tm], 0, 0, 0);
      accY[tm] = __builtin_amdgcn_mfma_f32_16x16x32_bf16(aLl, bUh, accY[tm], 0, 0, 0);
      accY[tm] = __builtin_amdgcn_mfma_f32_16x16x32_bf16(aLl, bUl, accY[tm], 0, 0, 0);
    }
  }

  // ---- store Y: row = 16tm+4g+q, col = 16w+lr (full 64B segments) ----
  float* __restrict__ Yg = Yout + (size_t)b * NN;
#pragma unroll
  for (int tm = 0; tm < 4; ++tm)
#pragma unroll
    for (int q = 0; q < 4; ++q)
      Yg[(16 * tm + 4 * g + q) * NDIM + 16 * w + lr] = accY[tm][q];
}

// ---------------------------------------------------------------------------
extern "C" void kernel_launch(void* const* d_in, const int* in_sizes, int n_in,
                              void* d_out, int out_size, void* d_ws,
                              size_t ws_size, hipStream_t stream) {
  const float* X    = (const float*)d_in[0];
  const float* rm   = (const float*)d_in[1];
  const float* bias = (const float*)d_in[2];
  float* out = (float*)d_out;
  float* ws  = (float*)d_ws;
  const int nmat = in_sizes[0] / NN;

  ns_roots_kernel<<<dim3(2), dim3(256), 0, stream>>>(rm, bias, ws);
  lt_kernel<<<dim3(1), dim3(256), 0, stream>>>(ws);
  bnspd_apply_mfma<<<dim3(nmat), dim3(256), 0, stream>>>(X, ws, out);
}